// Round 4
// baseline (141.444 us; speedup 1.0000x reference)
//
#include <hip/hip_runtime.h>

#define IN_DIM  2048
#define OUT_DIM 4096

typedef float     f32x4 __attribute__((ext_vector_type(4)));
typedef long long llx2  __attribute__((ext_vector_type(2)));

// pack 4 fp32 -> 4 fp8 e4m3 (RNE, HW)
__device__ __forceinline__ unsigned int pk4(float a, float b, float c, float d) {
    int v = __builtin_amdgcn_cvt_pk_fp8_f32(a, b, 0, false);   // bytes 0-1
    v     = __builtin_amdgcn_cvt_pk_fp8_f32(c, d, v, true);    // bytes 2-3
    return (unsigned int)v;
}

// k-interleaved fp8 row layout: within each 64B-aligned k-block, memory
// 8B-granule g holds logical k-chunk c(g) = (g>>1) + 4*(g&1); inverse
// g(c) = 2*(c&3)+(c>>2).  => 16B position p holds chunks {p, p+4}, i.e. the
// (kk=0,qd=p) and (kk=1,qd=p) fragments: one b128 read = 2 fp8 fragments.
__device__ __forceinline__ int gmem_of(int c) { return 2 * (c & 3) + (c >> 2); }

// --------------------------------------------------------------------------
// Kernel 1: fused prep (unchanged; ~10-14 us, near HBM floor).
// --------------------------------------------------------------------------
extern "C" __global__ __launch_bounds__(256) void prep(
        const float* __restrict__ W, const float* __restrict__ x,
        unsigned char* __restrict__ protos, unsigned char* __restrict__ xb,
        float* __restrict__ psq_part, float* __restrict__ x_sq) {
    __shared__ float tile[64][65];   // [d][c], +1 pad (z==2 uses [0][0..3])
    const int t = threadIdx.x;

    if (blockIdx.z == 2) {
        const int b = blockIdx.x + 32 * blockIdx.y;
        const float* xp = x + (size_t)b * IN_DIM + t * 8;
        const float4 v0 = ((const float4*)xp)[0];
        const float4 v1 = ((const float4*)xp)[1];
        uint2 pk;
        pk.x = pk4(v0.x, v0.y, v0.z, v0.w);
        pk.y = pk4(v1.x, v1.y, v1.z, v1.w);
        // t*8 elems = k-block t>>3, chunk t&7 -> interleaved granule position
        *(uint2*)(xb + (size_t)b * IN_DIM + (t >> 3) * 64 + gmem_of(t & 7) * 8) = pk;

        float s = v0.x * v0.x + v0.y * v0.y + v0.z * v0.z + v0.w * v0.w
                + v1.x * v1.x + v1.y * v1.y + v1.z * v1.z + v1.w * v1.w;
#pragma unroll
        for (int off = 32; off > 0; off >>= 1) s += __shfl_down(s, off);
        const int lane = t & 63, w = t >> 6;
        if (lane == 0) tile[0][w] = s;
        __syncthreads();
        if (t == 0) x_sq[b] = tile[0][0] + tile[0][1] + tile[0][2] + tile[0][3];
        return;
    }

    const int r  = blockIdx.z;
    const int c0 = blockIdx.x * 64;
    const int d0 = blockIdx.y * 64;
    const int g  = t >> 4;
    const int cc = (t & 15) * 4;

    const float* Wp = W + (size_t)(r * IN_DIM + d0 + g) * IN_DIM + c0 + cc;
#pragma unroll
    for (int p = 0; p < 4; ++p) {
        const float4 v = *(const float4*)(Wp + (size_t)(16 * p) * IN_DIM);
        const int dl = g + 16 * p;
        tile[dl][cc]     = v.x;
        tile[dl][cc + 1] = v.y;
        tile[dl][cc + 2] = v.z;
        tile[dl][cc + 3] = v.w;
    }
    __syncthreads();

    const int c8 = t & 7;                 // k-chunk within the 64-d tile
    const int gm = gmem_of(c8);
#pragma unroll
    for (int p = 0; p < 2; ++p) {
        const int cr = (t >> 3) + 32 * p; // c-row 0..63
        float v[8];
        float ss = 0.f;
#pragma unroll
        for (int j = 0; j < 8; ++j) {     // banks (8c8+j+cr)%32 -> 2-way, free
            v[j] = tile[8 * c8 + j][cr];
            ss += v[j] * v[j];
        }
        const int o = 2 * (c0 + cr) + r;
        uint2 pk;
        pk.x = pk4(16.f * v[0], 16.f * v[1], 16.f * v[2], 16.f * v[3]);
        pk.y = pk4(16.f * v[4], 16.f * v[5], 16.f * v[6], 16.f * v[7]);
        *(uint2*)(protos + (size_t)o * IN_DIM + d0 + gm * 8) = pk;
        ss += __shfl_xor(ss, 1);
        ss += __shfl_xor(ss, 2);
        ss += __shfl_xor(ss, 4);
        if (c8 == 0) psq_part[(size_t)blockIdx.y * OUT_DIM + o] = ss;
    }
}

// --------------------------------------------------------------------------
// Kernel 2: fp8 GEMM + epilogue — R12: barrier-free, LDS-free.
// Theory: all operands are per-XCD L2-resident (A 2MB + B panel 1MB < 4MB
// with the swizzle); the k-interleaved layout makes a 16B global read at
// row*2048 + it*64 + qd*16 exactly one MFMA fragment pair (same bytes the
// old LDS path delivered). Staging through LDS was pure overhead plus a
// vmcnt(0)+barrier drain every iteration that HIP cannot pipeline through
// (m99-m141; R10/R11 confirmed locally). With no barriers and no LDS the
// compiler pipelines loads across iterations freely.
// Structure: 512 blocks x 256 thr; block 64M x 128N; wave w owns 64M x 32N
// (acc[4][2], full K -> no split-K reduction, all threads run the epilogue).
// 2 blocks/CU (2 waves/SIMD); no min-waves clause -> 256-VGPR budget, no
// spill. Coalescing: each b128 frag load = 16 rows x one 64B line (the 4 qd
// lanes cover the full line). A lines are shared by all 4 waves (L1 reuse).
// --------------------------------------------------------------------------
extern "C" __global__ __launch_bounds__(256) void gemm_epi(
        const unsigned char* __restrict__ A,
        const unsigned char* __restrict__ Bt,
        const float* __restrict__ x_sq,
        const float* __restrict__ psq_part,
        const float* __restrict__ bias,
        float* __restrict__ out) {
    // XCD swizzle: XCD k owns n-tiles [4k, 4k+4) -> B panel 4x128 rows = 1MB
    // plus all of A (2MB) resident in that XCD's L2.
    const int lid = blockIdx.x;
    const int xcd = lid & 7;
    const int wi  = lid >> 3;            // 0..63
    const int nt  = xcd * 4 + (wi & 3);  // 0..31
    const int mt  = wi >> 2;             // 0..15
    const int m0 = mt * 64;
    const int n0 = nt * 128;

    const int t = threadIdx.x;
    const int wave = t >> 6;             // n-slice within block
    const int lane = t & 63;
    const int ln = lane & 15;
    const int qd = lane >> 4;

    // fragment base pointers: row*2048 + qd*16; k-step adds it*64.
    const unsigned char* gA = A  + (size_t)(m0 + ln) * IN_DIM + qd * 16;
    const unsigned char* gB = Bt + (size_t)(n0 + wave * 32 + ln) * IN_DIM + qd * 16;

    f32x4 acc[4][2] = {};

    for (int it = 0; it < 32; ++it) {    // BK=64, full K=2048 per wave
        llx2 af[4], bf[2];
#pragma unroll
        for (int i = 0; i < 4; ++i)
            af[i] = *(const llx2*)(gA + (size_t)(i * 16) * IN_DIM + it * 64);
#pragma unroll
        for (int j = 0; j < 2; ++j)
            bf[j] = *(const llx2*)(gB + (size_t)(j * 16) * IN_DIM + it * 64);
#pragma unroll
        for (int kk = 0; kk < 2; ++kk)
#pragma unroll
            for (int i = 0; i < 4; ++i)
#pragma unroll
                for (int j = 0; j < 2; ++j)
                    acc[i][j] = __builtin_amdgcn_mfma_f32_16x16x32_fp8_fp8(
                                    af[i][kk], bf[j][kk], acc[i][j], 0, 0, 0);
    }

    // epilogue: every thread stores its own 32 outputs (no split-K reduce).
    // C/D layout 16x16: col = ln, row = qd*4 + reg (m89).
#pragma unroll
    for (int j = 0; j < 2; ++j) {
        const int col = n0 + wave * 32 + j * 16 + ln;
        float pb = bias[col];
#pragma unroll
        for (int dt = 0; dt < 32; ++dt)
            pb += psq_part[(size_t)dt * OUT_DIM + col];
#pragma unroll
        for (int i = 0; i < 4; ++i) {
            const int row0 = m0 + i * 16 + qd * 4;
#pragma unroll
            for (int rr = 0; rr < 4; ++rr) {
                const int row = row0 + rr;
                out[(size_t)row * OUT_DIM + col] =
                    0.125f * acc[i][j][rr] - x_sq[row] - pb;
            }
        }
    }
}

// --------------------------------------------------------------------------
extern "C" void kernel_launch(void* const* d_in, const int* in_sizes, int n_in,
                              void* d_out, int out_size, void* d_ws, size_t ws_size,
                              hipStream_t stream) {
    const float* x    = (const float*)d_in[0];   // [1024, 2048]
    const float* W    = (const float*)d_in[1];   // [4096, 2048]
    const float* bias = (const float*)d_in[2];   // [4096]
    float* out = (float*)d_out;

    char* ws = (char*)d_ws;
    unsigned char* protos = (unsigned char*)ws;                               // 8 MB
    unsigned char* xb     = (unsigned char*)(ws + (size_t)8 * 1024 * 1024);   // 2 MB
    float* x_sq           = (float*)(ws + (size_t)10 * 1024 * 1024);          // 4 KB
    float* psq_part       = (float*)(ws + (size_t)10 * 1024 * 1024 + 65536);  // 512 KB

    prep<<<dim3(32, 32, 3), 256, 0, stream>>>(W, x, protos, xb, psq_part, x_sq);
    gemm_epi<<<dim3(512), 256, 0, stream>>>(xb, protos, x_sq, psq_part, bias, out);
}

// Round 5
// 117.519 us; speedup vs baseline: 1.2036x; 1.2036x over previous
//
#include <hip/hip_runtime.h>

#define IN_DIM  2048
#define OUT_DIM 4096

typedef float     f32x4 __attribute__((ext_vector_type(4)));
typedef long long llx2  __attribute__((ext_vector_type(2)));

// pack 4 fp32 -> 4 fp8 e4m3 (RNE, HW)
__device__ __forceinline__ unsigned int pk4(float a, float b, float c, float d) {
    int v = __builtin_amdgcn_cvt_pk_fp8_f32(a, b, 0, false);   // bytes 0-1
    v     = __builtin_amdgcn_cvt_pk_fp8_f32(c, d, v, true);    // bytes 2-3
    return (unsigned int)v;
}

// async global->LDS, 16B/lane; LDS dest must be wave-uniform base + lane*16
__device__ __forceinline__ void async16(const void* g, void* l) {
    __builtin_amdgcn_global_load_lds(
        (const __attribute__((address_space(1))) unsigned int*)g,
        (__attribute__((address_space(3))) unsigned int*)l,
        16, 0, 0);
}

// k-interleaved fp8 row layout: within each 64B-aligned k-block, memory
// 8B-granule g holds logical k-chunk c(g) = (g>>1) + 4*(g&1); inverse
// g(c) = 2*(c&3)+(c>>2).  => 16B position p holds chunks {p, p+4}, i.e. the
// (kk=0,qd=p) and (kk=1,qd=p) fragments: one ds_read_b128 = 2 fp8 fragments.
__device__ __forceinline__ int gmem_of(int c) { return 2 * (c & 3) + (c >> 2); }

// --------------------------------------------------------------------------
// Kernel 1: fused prep (unchanged; ~10-14 us, near HBM floor).
// --------------------------------------------------------------------------
extern "C" __global__ __launch_bounds__(256) void prep(
        const float* __restrict__ W, const float* __restrict__ x,
        unsigned char* __restrict__ protos, unsigned char* __restrict__ xb,
        float* __restrict__ psq_part, float* __restrict__ x_sq) {
    __shared__ float tile[64][65];   // [d][c], +1 pad (z==2 uses [0][0..3])
    const int t = threadIdx.x;

    if (blockIdx.z == 2) {
        const int b = blockIdx.x + 32 * blockIdx.y;
        const float* xp = x + (size_t)b * IN_DIM + t * 8;
        const float4 v0 = ((const float4*)xp)[0];
        const float4 v1 = ((const float4*)xp)[1];
        uint2 pk;
        pk.x = pk4(v0.x, v0.y, v0.z, v0.w);
        pk.y = pk4(v1.x, v1.y, v1.z, v1.w);
        // t*8 elems = k-block t>>3, chunk t&7 -> interleaved granule position
        *(uint2*)(xb + (size_t)b * IN_DIM + (t >> 3) * 64 + gmem_of(t & 7) * 8) = pk;

        float s = v0.x * v0.x + v0.y * v0.y + v0.z * v0.z + v0.w * v0.w
                + v1.x * v1.x + v1.y * v1.y + v1.z * v1.z + v1.w * v1.w;
#pragma unroll
        for (int off = 32; off > 0; off >>= 1) s += __shfl_down(s, off);
        const int lane = t & 63, w = t >> 6;
        if (lane == 0) tile[0][w] = s;
        __syncthreads();
        if (t == 0) x_sq[b] = tile[0][0] + tile[0][1] + tile[0][2] + tile[0][3];
        return;
    }

    const int r  = blockIdx.z;
    const int c0 = blockIdx.x * 64;
    const int d0 = blockIdx.y * 64;
    const int g  = t >> 4;
    const int cc = (t & 15) * 4;

    const float* Wp = W + (size_t)(r * IN_DIM + d0 + g) * IN_DIM + c0 + cc;
#pragma unroll
    for (int p = 0; p < 4; ++p) {
        const float4 v = *(const float4*)(Wp + (size_t)(16 * p) * IN_DIM);
        const int dl = g + 16 * p;
        tile[dl][cc]     = v.x;
        tile[dl][cc + 1] = v.y;
        tile[dl][cc + 2] = v.z;
        tile[dl][cc + 3] = v.w;
    }
    __syncthreads();

    const int c8 = t & 7;                 // k-chunk within the 64-d tile
    const int gm = gmem_of(c8);
#pragma unroll
    for (int p = 0; p < 2; ++p) {
        const int cr = (t >> 3) + 32 * p; // c-row 0..63
        float v[8];
        float ss = 0.f;
#pragma unroll
        for (int j = 0; j < 8; ++j) {     // banks (8c8+j+cr)%32 -> 2-way, free
            v[j] = tile[8 * c8 + j][cr];
            ss += v[j] * v[j];
        }
        const int o = 2 * (c0 + cr) + r;
        uint2 pk;
        pk.x = pk4(16.f * v[0], 16.f * v[1], 16.f * v[2], 16.f * v[3]);
        pk.y = pk4(16.f * v[4], 16.f * v[5], 16.f * v[6], 16.f * v[7]);
        *(uint2*)(protos + (size_t)o * IN_DIM + d0 + gm * 8) = pk;
        ss += __shfl_xor(ss, 1);
        ss += __shfl_xor(ss, 2);
        ss += __shfl_xor(ss, 4);
        if (c8 == 0) psq_part[(size_t)blockIdx.y * OUT_DIM + o] = ss;
    }
}

// --------------------------------------------------------------------------
// Kernel 2: fp8 GEMM + epilogue — R13: exact R7 structure (the session's
// measured best; every sync-structure mutation R10-R12 regressed), with ONE
// amortization change: stage TWO 64B k-blocks per barrier pair (BK=128 per
// K-half per iter, 8 iters instead of 16). The vmcnt(0)+s_barrier drain --
// the structural stall of this 2-barrier loop -- is paid 16x instead of 32x.
// LDS 32 KB (A 16 KB = 2 x 8 KB k-block tiles, B same): 4 blocks/CU x 32 KB
// = 128 KB <= 160 KB, occupancy unchanged (unlike m132's BK=128 case).
// Fragment addressing identical to R7; second k-block = +8192 LDS offset.
// acc[4][2] unchanged -> no spill under the (256,4) 128-VGPR cap (R8 lesson).
// --------------------------------------------------------------------------
extern "C" __global__ __launch_bounds__(256, 4) void gemm_epi(
        const unsigned char* __restrict__ A,
        const unsigned char* __restrict__ Bt,
        const float* __restrict__ x_sq,
        const float* __restrict__ psq_part,
        const float* __restrict__ bias,
        float* __restrict__ out) {
    __shared__ __align__(16) unsigned char smem[32768];
    unsigned char* lA = smem;            // 16 KB: 2 k-blocks x (64 rows x 128 B)
    unsigned char* lB = smem + 16384;    // 16 KB

    const int lid = blockIdx.x;          // XCD swizzle: XCD k owns n-tiles [8k,8k+8)
    const int xcd = lid & 7;
    const int wi  = lid >> 3;
    const int nt  = xcd * 8 + (wi & 7);
    const int mt  = wi >> 3;
    const int m0 = mt * 64;
    const int n0 = nt * 64;

    const int t = threadIdx.x;
    // staging: thread t owns LDS bytes [16t,16t+16) and [4096+16t,+16) of
    // each 8 KB k-block tile. off -> row=off>>7, phys pos p=(off>>4)&7;
    // logical l = p^(row&7); l -> k-half l>>2, 16B-chunk l&3 of the 64B block.
    const int rS = t >> 3;               // row 0..31 (2nd chunk: +32, same &7)
    const int pS = t & 7;
    const int lS = pS ^ (rS & 7);
    const size_t goff = (size_t)(lS >> 2) * 1024 + (lS & 3) * 16;
    const unsigned char* gA0 = A  + (size_t)(m0 + rS) * IN_DIM + goff;
    const unsigned char* gA1 = gA0 + (size_t)32 * IN_DIM;
    const unsigned char* gB0 = Bt + (size_t)(n0 + rS) * IN_DIM + goff;
    const unsigned char* gB1 = gB0 + (size_t)32 * IN_DIM;
    unsigned char* lAd = lA + t * 16;
    unsigned char* lBd = lB + t * 16;

    const int wave = t >> 6;
    const int lane = t & 63;
    const int kh = wave & 1;             // K-half this wave owns
    const int nh = wave >> 1;            // N-half this wave owns
    const int ln = lane & 15;
    const int qd = lane >> 4;
    const int pr = (kh * 4 + qd) ^ (ln & 7);   // phys 16B pos for frag reads

    f32x4 acc[4][2] = {};

    for (int it = 0; it < 8; ++it) {     // BK=128 per half per iter
        // k-block 0 -> LDS [0,8K), k-block 1 (global +64) -> LDS [8K,16K)
        async16(gA0,      lAd);        async16(gA1,      lAd + 4096);
        async16(gA0 + 64, lAd + 8192); async16(gA1 + 64, lAd + 12288);
        async16(gB0,      lBd);        async16(gB1,      lBd + 4096);
        async16(gB0 + 64, lBd + 8192); async16(gB1 + 64, lBd + 12288);
        gA0 += 128; gA1 += 128; gB0 += 128; gB1 += 128;
        __syncthreads();                 // vmcnt drain: both k-blocks visible

#pragma unroll
        for (int h = 0; h < 2; ++h) {
            const int hb = h * 8192;
            llx2 af[4], bf[2];
#pragma unroll
            for (int i = 0; i < 4; ++i)
                af[i] = *(const llx2*)(lA + hb + (i * 16 + ln) * 128 + pr * 16);
#pragma unroll
            for (int j = 0; j < 2; ++j)
                bf[j] = *(const llx2*)(lB + hb + (nh * 32 + j * 16 + ln) * 128 + pr * 16);
#pragma unroll
            for (int kk = 0; kk < 2; ++kk)
#pragma unroll
                for (int i = 0; i < 4; ++i)
#pragma unroll
                    for (int j = 0; j < 2; ++j)
                        acc[i][j] = __builtin_amdgcn_mfma_f32_16x16x32_fp8_fp8(
                                        af[i][kk], bf[j][kk], acc[i][j], 0, 0, 0);
        }
        __syncthreads();                 // reads done before next stage
    }

    // cross-K-half reduction: kh=1 waves dump acc to LDS, kh=0 waves finish.
    if (kh == 1) {
#pragma unroll
        for (int i = 0; i < 4; ++i)
#pragma unroll
            for (int j = 0; j < 2; ++j)
                *(f32x4*)(smem + nh * 8192 + (i * 2 + j) * 1024 + lane * 16) =
                    acc[i][j];
    }
    __syncthreads();
    if (kh == 0) {
#pragma unroll
        for (int j = 0; j < 2; ++j) {
            const int col = n0 + nh * 32 + j * 16 + ln;
            float pb = bias[col];
#pragma unroll
            for (int dt = 0; dt < 32; ++dt)
                pb += psq_part[(size_t)dt * OUT_DIM + col];
#pragma unroll
            for (int i = 0; i < 4; ++i) {
                const f32x4 o4 = *(const f32x4*)(smem + nh * 8192 +
                                                 (i * 2 + j) * 1024 + lane * 16);
                const int row0 = m0 + i * 16 + qd * 4;
#pragma unroll
                for (int rr = 0; rr < 4; ++rr) {
                    const int row = row0 + rr;
                    out[(size_t)row * OUT_DIM + col] =
                        0.125f * (acc[i][j][rr] + o4[rr]) - x_sq[row] - pb;
                }
            }
        }
    }
}

// --------------------------------------------------------------------------
extern "C" void kernel_launch(void* const* d_in, const int* in_sizes, int n_in,
                              void* d_out, int out_size, void* d_ws, size_t ws_size,
                              hipStream_t stream) {
    const float* x    = (const float*)d_in[0];   // [1024, 2048]
    const float* W    = (const float*)d_in[1];   // [4096, 2048]
    const float* bias = (const float*)d_in[2];   // [4096]
    float* out = (float*)d_out;

    char* ws = (char*)d_ws;
    unsigned char* protos = (unsigned char*)ws;                               // 8 MB
    unsigned char* xb     = (unsigned char*)(ws + (size_t)8 * 1024 * 1024);   // 2 MB
    float* x_sq           = (float*)(ws + (size_t)10 * 1024 * 1024);          // 4 KB
    float* psq_part       = (float*)(ws + (size_t)10 * 1024 * 1024 + 65536);  // 512 KB

    prep<<<dim3(32, 32, 3), 256, 0, stream>>>(W, x, protos, xb, psq_part, x_sq);
    gemm_epi<<<dim3(1024), 256, 0, stream>>>(xb, protos, x_sq, psq_part, bias, out);
}

// Round 6
// 114.861 us; speedup vs baseline: 1.2314x; 1.0231x over previous
//
#include <hip/hip_runtime.h>

#define IN_DIM  2048
#define OUT_DIM 4096

typedef float     f32x4 __attribute__((ext_vector_type(4)));
typedef long long llx2  __attribute__((ext_vector_type(2)));

// pack 4 fp32 -> 4 fp8 e4m3 (RNE, HW)
__device__ __forceinline__ unsigned int pk4(float a, float b, float c, float d) {
    int v = __builtin_amdgcn_cvt_pk_fp8_f32(a, b, 0, false);   // bytes 0-1
    v     = __builtin_amdgcn_cvt_pk_fp8_f32(c, d, v, true);    // bytes 2-3
    return (unsigned int)v;
}

// async global->LDS, 16B/lane; LDS dest must be wave-uniform base + lane*16
__device__ __forceinline__ void async16(const void* g, void* l) {
    __builtin_amdgcn_global_load_lds(
        (const __attribute__((address_space(1))) unsigned int*)g,
        (__attribute__((address_space(3))) unsigned int*)l,
        16, 0, 0);
}

// k-interleaved fp8 row layout: within each 64B-aligned k-block, memory
// 8B-granule g holds logical k-chunk c(g) = (g>>1) + 4*(g&1); inverse
// g(c) = 2*(c&3)+(c>>2).  => 16B position p holds chunks {p, p+4}, i.e. the
// (kk=0,qd=p) and (kk=1,qd=p) fragments: one ds_read_b128 = 2 fp8 fragments.
__device__ __forceinline__ int gmem_of(int c) { return 2 * (c & 3) + (c >> 2); }

// --------------------------------------------------------------------------
// Kernel 1: fused prep (unchanged; ~12 us, near HBM floor).
// --------------------------------------------------------------------------
extern "C" __global__ __launch_bounds__(256) void prep(
        const float* __restrict__ W, const float* __restrict__ x,
        unsigned char* __restrict__ protos, unsigned char* __restrict__ xb,
        float* __restrict__ psq_part, float* __restrict__ x_sq) {
    __shared__ float tile[64][65];   // [d][c], +1 pad (z==2 uses [0][0..3])
    const int t = threadIdx.x;

    if (blockIdx.z == 2) {
        const int b = blockIdx.x + 32 * blockIdx.y;
        const float* xp = x + (size_t)b * IN_DIM + t * 8;
        const float4 v0 = ((const float4*)xp)[0];
        const float4 v1 = ((const float4*)xp)[1];
        uint2 pk;
        pk.x = pk4(v0.x, v0.y, v0.z, v0.w);
        pk.y = pk4(v1.x, v1.y, v1.z, v1.w);
        // t*8 elems = k-block t>>3, chunk t&7 -> interleaved granule position
        *(uint2*)(xb + (size_t)b * IN_DIM + (t >> 3) * 64 + gmem_of(t & 7) * 8) = pk;

        float s = v0.x * v0.x + v0.y * v0.y + v0.z * v0.z + v0.w * v0.w
                + v1.x * v1.x + v1.y * v1.y + v1.z * v1.z + v1.w * v1.w;
#pragma unroll
        for (int off = 32; off > 0; off >>= 1) s += __shfl_down(s, off);
        const int lane = t & 63, w = t >> 6;
        if (lane == 0) tile[0][w] = s;
        __syncthreads();
        if (t == 0) x_sq[b] = tile[0][0] + tile[0][1] + tile[0][2] + tile[0][3];
        return;
    }

    const int r  = blockIdx.z;
    const int c0 = blockIdx.x * 64;
    const int d0 = blockIdx.y * 64;
    const int g  = t >> 4;
    const int cc = (t & 15) * 4;

    const float* Wp = W + (size_t)(r * IN_DIM + d0 + g) * IN_DIM + c0 + cc;
#pragma unroll
    for (int p = 0; p < 4; ++p) {
        const float4 v = *(const float4*)(Wp + (size_t)(16 * p) * IN_DIM);
        const int dl = g + 16 * p;
        tile[dl][cc]     = v.x;
        tile[dl][cc + 1] = v.y;
        tile[dl][cc + 2] = v.z;
        tile[dl][cc + 3] = v.w;
    }
    __syncthreads();

    const int c8 = t & 7;                 // k-chunk within the 64-d tile
    const int gm = gmem_of(c8);
#pragma unroll
    for (int p = 0; p < 2; ++p) {
        const int cr = (t >> 3) + 32 * p; // c-row 0..63
        float v[8];
        float ss = 0.f;
#pragma unroll
        for (int j = 0; j < 8; ++j) {     // banks (8c8+j+cr)%32 -> 2-way, free
            v[j] = tile[8 * c8 + j][cr];
            ss += v[j] * v[j];
        }
        const int o = 2 * (c0 + cr) + r;
        uint2 pk;
        pk.x = pk4(16.f * v[0], 16.f * v[1], 16.f * v[2], 16.f * v[3]);
        pk.y = pk4(16.f * v[4], 16.f * v[5], 16.f * v[6], 16.f * v[7]);
        *(uint2*)(protos + (size_t)o * IN_DIM + d0 + gm * 8) = pk;
        ss += __shfl_xor(ss, 1);
        ss += __shfl_xor(ss, 2);
        ss += __shfl_xor(ss, 4);
        if (c8 == 0) psq_part[(size_t)blockIdx.y * OUT_DIM + o] = ss;
    }
}

// --------------------------------------------------------------------------
// Kernel 2: fp8 GEMM + epilogue — R14: K-loop reverted BYTE-EXACT to R7
// (verified session best, 108.7). Session record: R10 (asm pipeline), R11
// (direct B loads), R12 (no LDS), R13 (BK=128) ALL regressed — the 2-barrier
// single-buffer loop at 4 blocks/CU is a local optimum (cross-block TLP does
// the latency hiding, m114; the vmcnt drain waits on the load TAIL, so
// barrier-count amortization is a no-op, R13 lesson).
// ONE additive change: hoist the epilogue's bias+psq_part reduction (66
// dependent L2 loads/thread, previously a serial tail after the last
// barrier) to BEFORE the K-loop — latency hides under tile-0 staging and
// the loop. Held state: pb[2] (2 VGPR). Math order identical.
// --------------------------------------------------------------------------
extern "C" __global__ __launch_bounds__(256, 4) void gemm_epi(
        const unsigned char* __restrict__ A,
        const unsigned char* __restrict__ Bt,
        const float* __restrict__ x_sq,
        const float* __restrict__ psq_part,
        const float* __restrict__ bias,
        float* __restrict__ out) {
    __shared__ __align__(16) unsigned char smem[16384];
    unsigned char* lA = smem;           // 8 KB: 64 rows x 128 B
    unsigned char* lB = smem + 8192;    // 8 KB

    const int lid = blockIdx.x;          // XCD swizzle: XCD k owns n-tiles [8k,8k+8)
    const int xcd = lid & 7;
    const int wi  = lid >> 3;
    const int nt  = xcd * 8 + (wi & 7);
    const int mt  = wi >> 3;
    const int m0 = mt * 64;
    const int n0 = nt * 64;

    const int t = threadIdx.x;
    // staging: thread t owns LDS bytes [16t,16t+16) and [4096+16t,+16) of
    // lA/lB. off -> row=off>>7, phys pos p=(off>>4)&7; logical l = p^(row&7);
    // l -> k-half l>>2, 16B-chunk l&3 of the row's 64B k-block.
    const int rS = t >> 3;               // row 0..31 (2nd chunk: +32, same &7)
    const int pS = t & 7;
    const int lS = pS ^ (rS & 7);
    const size_t goff = (size_t)(lS >> 2) * 1024 + (lS & 3) * 16;
    const unsigned char* gA0 = A  + (size_t)(m0 + rS) * IN_DIM + goff;
    const unsigned char* gA1 = gA0 + (size_t)32 * IN_DIM;
    const unsigned char* gB0 = Bt + (size_t)(n0 + rS) * IN_DIM + goff;
    const unsigned char* gB1 = gB0 + (size_t)32 * IN_DIM;
    unsigned char* lAd = lA + t * 16;
    unsigned char* lBd = lB + t * 16;

    const int wave = t >> 6;
    const int lane = t & 63;
    const int kh = wave & 1;             // K-half this wave owns
    const int nh = wave >> 1;            // N-half this wave owns
    const int ln = lane & 15;
    const int qd = lane >> 4;
    const int pr = (kh * 4 + qd) ^ (ln & 7);   // phys 16B pos for frag reads

    // epilogue-operand prefetch (R14): compute pb[j] = bias + sum_dt psq_part
    // up front; the ~66 L2 loads overlap the first tile staging + K-loop.
    float pb[2];
#pragma unroll
    for (int j = 0; j < 2; ++j) {
        const int col = n0 + nh * 32 + j * 16 + ln;
        float s = bias[col];
#pragma unroll
        for (int dt = 0; dt < 32; ++dt)
            s += psq_part[(size_t)dt * OUT_DIM + col];
        pb[j] = s;
    }

    f32x4 acc[4][2] = {};

    for (int it = 0; it < 16; ++it) {    // BK=64 per half per iter
        async16(gA0, lAd); async16(gA1, lAd + 4096);
        async16(gB0, lBd); async16(gB1, lBd + 4096);
        gA0 += 64; gA1 += 64; gB0 += 64; gB1 += 64;
        __syncthreads();                 // vmcnt drain: tile visible

        llx2 af[4], bf[2];
#pragma unroll
        for (int i = 0; i < 4; ++i)
            af[i] = *(const llx2*)(lA + (i * 16 + ln) * 128 + pr * 16);
#pragma unroll
        for (int j = 0; j < 2; ++j)
            bf[j] = *(const llx2*)(lB + (nh * 32 + j * 16 + ln) * 128 + pr * 16);
#pragma unroll
        for (int kk = 0; kk < 2; ++kk)
#pragma unroll
            for (int i = 0; i < 4; ++i)
#pragma unroll
                for (int j = 0; j < 2; ++j)
                    acc[i][j] = __builtin_amdgcn_mfma_f32_16x16x32_fp8_fp8(
                                    af[i][kk], bf[j][kk], acc[i][j], 0, 0, 0);
        __syncthreads();                 // reads done before next stage
    }

    // cross-K-half reduction: kh=1 waves dump acc to LDS, kh=0 waves finish.
    if (kh == 1) {
#pragma unroll
        for (int i = 0; i < 4; ++i)
#pragma unroll
            for (int j = 0; j < 2; ++j)
                *(f32x4*)(smem + nh * 8192 + (i * 2 + j) * 1024 + lane * 16) =
                    acc[i][j];
    }
    __syncthreads();
    if (kh == 0) {
#pragma unroll
        for (int j = 0; j < 2; ++j) {
            const int col = n0 + nh * 32 + j * 16 + ln;
#pragma unroll
            for (int i = 0; i < 4; ++i) {
                const f32x4 o4 = *(const f32x4*)(smem + nh * 8192 +
                                                 (i * 2 + j) * 1024 + lane * 16);
                const int row0 = m0 + i * 16 + qd * 4;
#pragma unroll
                for (int rr = 0; rr < 4; ++rr) {
                    const int row = row0 + rr;
                    out[(size_t)row * OUT_DIM + col] =
                        0.125f * (acc[i][j][rr] + o4[rr]) - x_sq[row] - pb[j];
                }
            }
        }
    }
}

// --------------------------------------------------------------------------
extern "C" void kernel_launch(void* const* d_in, const int* in_sizes, int n_in,
                              void* d_out, int out_size, void* d_ws, size_t ws_size,
                              hipStream_t stream) {
    const float* x    = (const float*)d_in[0];   // [1024, 2048]
    const float* W    = (const float*)d_in[1];   // [4096, 2048]
    const float* bias = (const float*)d_in[2];   // [4096]
    float* out = (float*)d_out;

    char* ws = (char*)d_ws;
    unsigned char* protos = (unsigned char*)ws;                               // 8 MB
    unsigned char* xb     = (unsigned char*)(ws + (size_t)8 * 1024 * 1024);   // 2 MB
    float* x_sq           = (float*)(ws + (size_t)10 * 1024 * 1024);          // 4 KB
    float* psq_part       = (float*)(ws + (size_t)10 * 1024 * 1024 + 65536);  // 512 KB

    prep<<<dim3(32, 32, 3), 256, 0, stream>>>(W, x, protos, xb, psq_part, x_sq);
    gemm_epi<<<dim3(1024), 256, 0, stream>>>(xb, protos, x_sq, psq_part, bias, out);
}

// Round 7
// 110.620 us; speedup vs baseline: 1.2786x; 1.0383x over previous
//
#include <hip/hip_runtime.h>

#define IN_DIM  2048
#define OUT_DIM 4096

typedef float     f32x4 __attribute__((ext_vector_type(4)));
typedef long long llx2  __attribute__((ext_vector_type(2)));

// pack 4 fp32 -> 4 fp8 e4m3 (RNE, HW)
__device__ __forceinline__ unsigned int pk4(float a, float b, float c, float d) {
    int v = __builtin_amdgcn_cvt_pk_fp8_f32(a, b, 0, false);   // bytes 0-1
    v     = __builtin_amdgcn_cvt_pk_fp8_f32(c, d, v, true);    // bytes 2-3
    return (unsigned int)v;
}

// async global->LDS, 16B/lane; LDS dest must be wave-uniform base + lane*16
__device__ __forceinline__ void async16(const void* g, void* l) {
    __builtin_amdgcn_global_load_lds(
        (const __attribute__((address_space(1))) unsigned int*)g,
        (__attribute__((address_space(3))) unsigned int*)l,
        16, 0, 0);
}

// k-interleaved fp8 row layout: within each 64B-aligned k-block, memory
// 8B-granule g holds logical k-chunk c(g) = (g>>1) + 4*(g&1); inverse
// g(c) = 2*(c&3)+(c>>2).  => 16B position p holds chunks {p, p+4}, i.e. the
// (kk=0,qd=p) and (kk=1,qd=p) fragments: one ds_read_b128 = 2 fp8 fragments.
__device__ __forceinline__ int gmem_of(int c) { return 2 * (c & 3) + (c >> 2); }

// --------------------------------------------------------------------------
// Kernel 1: fused prep (unchanged; ~12 us, near HBM floor).
// --------------------------------------------------------------------------
extern "C" __global__ __launch_bounds__(256) void prep(
        const float* __restrict__ W, const float* __restrict__ x,
        unsigned char* __restrict__ protos, unsigned char* __restrict__ xb,
        float* __restrict__ psq_part, float* __restrict__ x_sq) {
    __shared__ float tile[64][65];   // [d][c], +1 pad (z==2 uses [0][0..3])
    const int t = threadIdx.x;

    if (blockIdx.z == 2) {
        const int b = blockIdx.x + 32 * blockIdx.y;
        const float* xp = x + (size_t)b * IN_DIM + t * 8;
        const float4 v0 = ((const float4*)xp)[0];
        const float4 v1 = ((const float4*)xp)[1];
        uint2 pk;
        pk.x = pk4(v0.x, v0.y, v0.z, v0.w);
        pk.y = pk4(v1.x, v1.y, v1.z, v1.w);
        // t*8 elems = k-block t>>3, chunk t&7 -> interleaved granule position
        *(uint2*)(xb + (size_t)b * IN_DIM + (t >> 3) * 64 + gmem_of(t & 7) * 8) = pk;

        float s = v0.x * v0.x + v0.y * v0.y + v0.z * v0.z + v0.w * v0.w
                + v1.x * v1.x + v1.y * v1.y + v1.z * v1.z + v1.w * v1.w;
#pragma unroll
        for (int off = 32; off > 0; off >>= 1) s += __shfl_down(s, off);
        const int lane = t & 63, w = t >> 6;
        if (lane == 0) tile[0][w] = s;
        __syncthreads();
        if (t == 0) x_sq[b] = tile[0][0] + tile[0][1] + tile[0][2] + tile[0][3];
        return;
    }

    const int r  = blockIdx.z;
    const int c0 = blockIdx.x * 64;
    const int d0 = blockIdx.y * 64;
    const int g  = t >> 4;
    const int cc = (t & 15) * 4;

    const float* Wp = W + (size_t)(r * IN_DIM + d0 + g) * IN_DIM + c0 + cc;
#pragma unroll
    for (int p = 0; p < 4; ++p) {
        const float4 v = *(const float4*)(Wp + (size_t)(16 * p) * IN_DIM);
        const int dl = g + 16 * p;
        tile[dl][cc]     = v.x;
        tile[dl][cc + 1] = v.y;
        tile[dl][cc + 2] = v.z;
        tile[dl][cc + 3] = v.w;
    }
    __syncthreads();

    const int c8 = t & 7;                 // k-chunk within the 64-d tile
    const int gm = gmem_of(c8);
#pragma unroll
    for (int p = 0; p < 2; ++p) {
        const int cr = (t >> 3) + 32 * p; // c-row 0..63
        float v[8];
        float ss = 0.f;
#pragma unroll
        for (int j = 0; j < 8; ++j) {     // banks (8c8+j+cr)%32 -> 2-way, free
            v[j] = tile[8 * c8 + j][cr];
            ss += v[j] * v[j];
        }
        const int o = 2 * (c0 + cr) + r;
        uint2 pk;
        pk.x = pk4(16.f * v[0], 16.f * v[1], 16.f * v[2], 16.f * v[3]);
        pk.y = pk4(16.f * v[4], 16.f * v[5], 16.f * v[6], 16.f * v[7]);
        *(uint2*)(protos + (size_t)o * IN_DIM + d0 + gm * 8) = pk;
        ss += __shfl_xor(ss, 1);
        ss += __shfl_xor(ss, 2);
        ss += __shfl_xor(ss, 4);
        if (c8 == 0) psq_part[(size_t)blockIdx.y * OUT_DIM + o] = ss;
    }
}

// --------------------------------------------------------------------------
// Kernel 2: fp8 GEMM + epilogue — R15: T3-minimum schedule in pure HIP.
// R7 staged tile t then IMMEDIATELY drained vmcnt(0) (zero overlap, 2
// barriers/iter). R10 added overlap but with asm pins that defeated the
// compiler (regressed). T3-min is the untried middle: double-buffer, issue
// stage(t+1) at the TOP of iter t, compute tile t, then ONE __syncthreads()
// per iter. No inline asm, no sched_barrier — the syncthreads drain happens
// after a full iteration (~350cy ds_read+MFMA) of overlap, so the stage
// latency is ~covered; barrier count 32 -> 17.
// Hazard audit: stage into buf^1 at iter t is ordered after iter t-1's
// barrier, by which point every wave's ds_reads of buf^1 were consumed
// (compiler lgkmcnt before MFMA) — single barrier suffices (same hazard
// structure R10 ran correctly). LDS 32 KB -> 4 blocks/CU unchanged (R13
// confirmed occupancy-neutral at 32 KB). acc[4][2], pb-hoist kept (R14).
// --------------------------------------------------------------------------
extern "C" __global__ __launch_bounds__(256, 4) void gemm_epi(
        const unsigned char* __restrict__ A,
        const unsigned char* __restrict__ Bt,
        const float* __restrict__ x_sq,
        const float* __restrict__ psq_part,
        const float* __restrict__ bias,
        float* __restrict__ out) {
    __shared__ __align__(16) unsigned char smem[32768];
    // buffer at smem+bb, bb in {0,16384}: A = [0,8192), B = [8192,16384)

    const int lid = blockIdx.x;          // XCD swizzle: XCD k owns n-tiles [8k,8k+8)
    const int xcd = lid & 7;
    const int wi  = lid >> 3;
    const int nt  = xcd * 8 + (wi & 7);
    const int mt  = wi >> 3;
    const int m0 = mt * 64;
    const int n0 = nt * 64;

    const int t = threadIdx.x;
    // staging: thread t owns bytes [16t,16t+16) and [4096+16t,+16) of each
    // half. off -> row=off>>7, phys pos p=(off>>4)&7; logical l = p^(row&7);
    // l -> k-half l>>2, 16B-chunk l&3 of the row's 64B k-block.
    const int rS = t >> 3;               // row 0..31 (2nd chunk: +32, same &7)
    const int pS = t & 7;
    const int lS = pS ^ (rS & 7);
    const size_t goff = (size_t)(lS >> 2) * 1024 + (lS & 3) * 16;
    const unsigned char* gA0 = A  + (size_t)(m0 + rS) * IN_DIM + goff;
    const unsigned char* gA1 = gA0 + (size_t)32 * IN_DIM;
    const unsigned char* gB0 = Bt + (size_t)(n0 + rS) * IN_DIM + goff;
    const unsigned char* gB1 = gB0 + (size_t)32 * IN_DIM;

    const int wave = t >> 6;
    const int lane = t & 63;
    const int kh = wave & 1;             // K-half this wave owns
    const int nh = wave >> 1;            // N-half this wave owns
    const int ln = lane & 15;
    const int qd = lane >> 4;
    const int pr = (kh * 4 + qd) ^ (ln & 7);   // phys 16B pos for frag reads

    // epilogue-operand prefetch (R14): pb[j] = bias + sum_dt psq_part; the
    // ~66 L2 loads overlap tile-0 staging + the K-loop.
    float pb[2];
#pragma unroll
    for (int j = 0; j < 2; ++j) {
        const int col = n0 + nh * 32 + j * 16 + ln;
        float s = bias[col];
#pragma unroll
        for (int dt = 0; dt < 32; ++dt)
            s += psq_part[(size_t)dt * OUT_DIM + col];
        pb[j] = s;
    }

    f32x4 acc[4][2] = {};

    // prologue: stage tile 0 into buffer 0
    async16(gA0, smem + t * 16);
    async16(gA1, smem + 4096 + t * 16);
    async16(gB0, smem + 8192 + t * 16);
    async16(gB1, smem + 12288 + t * 16);
    gA0 += 64; gA1 += 64; gB0 += 64; gB1 += 64;
    __syncthreads();                     // tile 0 visible

    int bb = 0;
    for (int it = 0; it < 16; ++it) {    // BK=64 per half per iter
        const int nb = bb ^ 16384;
        if (it < 15) {
            // stage tile it+1 now; its latency hides under THIS iteration's
            // ds_reads + 16 MFMAs before the end-of-iter syncthreads drain.
            async16(gA0, smem + nb + t * 16);
            async16(gA1, smem + nb + 4096 + t * 16);
            async16(gB0, smem + nb + 8192 + t * 16);
            async16(gB1, smem + nb + 12288 + t * 16);
            gA0 += 64; gA1 += 64; gB0 += 64; gB1 += 64;
        }

        const unsigned char* lA = smem + bb;
        const unsigned char* lB = smem + bb + 8192;
        llx2 af[4], bf[2];
#pragma unroll
        for (int i = 0; i < 4; ++i)
            af[i] = *(const llx2*)(lA + (i * 16 + ln) * 128 + pr * 16);
#pragma unroll
        for (int j = 0; j < 2; ++j)
            bf[j] = *(const llx2*)(lB + (nh * 32 + j * 16 + ln) * 128 + pr * 16);
#pragma unroll
        for (int kk = 0; kk < 2; ++kk)
#pragma unroll
            for (int i = 0; i < 4; ++i)
#pragma unroll
                for (int j = 0; j < 2; ++j)
                    acc[i][j] = __builtin_amdgcn_mfma_f32_16x16x32_fp8_fp8(
                                    af[i][kk], bf[j][kk], acc[i][j], 0, 0, 0);

        __syncthreads();                 // drain stage(it+1); reads of bb done
        bb = nb;
    }

    // cross-K-half reduction: kh=1 waves dump acc to LDS, kh=0 waves finish.
    if (kh == 1) {
#pragma unroll
        for (int i = 0; i < 4; ++i)
#pragma unroll
            for (int j = 0; j < 2; ++j)
                *(f32x4*)(smem + nh * 8192 + (i * 2 + j) * 1024 + lane * 16) =
                    acc[i][j];
    }
    __syncthreads();
    if (kh == 0) {
#pragma unroll
        for (int j = 0; j < 2; ++j) {
            const int col = n0 + nh * 32 + j * 16 + ln;
#pragma unroll
            for (int i = 0; i < 4; ++i) {
                const f32x4 o4 = *(const f32x4*)(smem + nh * 8192 +
                                                 (i * 2 + j) * 1024 + lane * 16);
                const int row0 = m0 + i * 16 + qd * 4;
#pragma unroll
                for (int rr = 0; rr < 4; ++rr) {
                    const int row = row0 + rr;
                    out[(size_t)row * OUT_DIM + col] =
                        0.125f * (acc[i][j][rr] + o4[rr]) - x_sq[row] - pb[j];
                }
            }
        }
    }
}

// --------------------------------------------------------------------------
extern "C" void kernel_launch(void* const* d_in, const int* in_sizes, int n_in,
                              void* d_out, int out_size, void* d_ws, size_t ws_size,
                              hipStream_t stream) {
    const float* x    = (const float*)d_in[0];   // [1024, 2048]
    const float* W    = (const float*)d_in[1];   // [4096, 2048]
    const float* bias = (const float*)d_in[2];   // [4096]
    float* out = (float*)d_out;

    char* ws = (char*)d_ws;
    unsigned char* protos = (unsigned char*)ws;                               // 8 MB
    unsigned char* xb     = (unsigned char*)(ws + (size_t)8 * 1024 * 1024);   // 2 MB
    float* x_sq           = (float*)(ws + (size_t)10 * 1024 * 1024);          // 4 KB
    float* psq_part       = (float*)(ws + (size_t)10 * 1024 * 1024 + 65536);  // 512 KB

    prep<<<dim3(32, 32, 3), 256, 0, stream>>>(W, x, protos, xb, psq_part, x_sq);
    gemm_epi<<<dim3(1024), 256, 0, stream>>>(xb, protos, x_sq, psq_part, bias, out);
}

// Round 8
// 107.524 us; speedup vs baseline: 1.3155x; 1.0288x over previous
//
#include <hip/hip_runtime.h>

#define IN_DIM  2048
#define OUT_DIM 4096

typedef float     f32x4 __attribute__((ext_vector_type(4)));
typedef long long llx2  __attribute__((ext_vector_type(2)));

// pack 4 fp32 -> 4 fp8 e4m3 (RNE, HW)
__device__ __forceinline__ unsigned int pk4(float a, float b, float c, float d) {
    int v = __builtin_amdgcn_cvt_pk_fp8_f32(a, b, 0, false);   // bytes 0-1
    v     = __builtin_amdgcn_cvt_pk_fp8_f32(c, d, v, true);    // bytes 2-3
    return (unsigned int)v;
}

// async global->LDS, 16B/lane; LDS dest must be wave-uniform base + lane*16
__device__ __forceinline__ void async16(const void* g, void* l) {
    __builtin_amdgcn_global_load_lds(
        (const __attribute__((address_space(1))) unsigned int*)g,
        (__attribute__((address_space(3))) unsigned int*)l,
        16, 0, 0);
}

// k-interleaved fp8 row layout: within each 64B-aligned k-block, memory
// 8B-granule g holds logical k-chunk c(g) = (g>>1) + 4*(g&1); inverse
// g(c) = 2*(c&3)+(c>>2).  => 16B position p holds chunks {p, p+4}, i.e. the
// (kk=0,qd=p) and (kk=1,qd=p) fragments: one ds_read_b128 = 2 fp8 fragments.
__device__ __forceinline__ int gmem_of(int c) { return 2 * (c & 3) + (c >> 2); }

// --------------------------------------------------------------------------
// Kernel 1: fused prep (2 dispatches total for the whole problem).
//  z<2  : transpose slice — W [4096][2048] fp32 -> protos fp8 (x16 scale,
//         k-interleaved), protos[2c+r][d] = fp8(16*W[r*2048+d][c]); exact
//         fp32 partial sumsq -> psq_part[dtile][o] (no atomics, no zeroing).
//  z==2 : xcast — x row b -> xb fp8 (k-interleaved), x_sq[b] exact fp32.
// grid (32, 32, 3) x 256 threads
// --------------------------------------------------------------------------
extern "C" __global__ __launch_bounds__(256) void prep(
        const float* __restrict__ W, const float* __restrict__ x,
        unsigned char* __restrict__ protos, unsigned char* __restrict__ xb,
        float* __restrict__ psq_part, float* __restrict__ x_sq) {
    __shared__ float tile[64][65];   // [d][c], +1 pad (z==2 uses [0][0..3])
    const int t = threadIdx.x;

    if (blockIdx.z == 2) {
        const int b = blockIdx.x + 32 * blockIdx.y;
        const float* xp = x + (size_t)b * IN_DIM + t * 8;
        const float4 v0 = ((const float4*)xp)[0];
        const float4 v1 = ((const float4*)xp)[1];
        uint2 pk;
        pk.x = pk4(v0.x, v0.y, v0.z, v0.w);
        pk.y = pk4(v1.x, v1.y, v1.z, v1.w);
        // t*8 elems = k-block t>>3, chunk t&7 -> interleaved granule position
        *(uint2*)(xb + (size_t)b * IN_DIM + (t >> 3) * 64 + gmem_of(t & 7) * 8) = pk;

        float s = v0.x * v0.x + v0.y * v0.y + v0.z * v0.z + v0.w * v0.w
                + v1.x * v1.x + v1.y * v1.y + v1.z * v1.z + v1.w * v1.w;
#pragma unroll
        for (int off = 32; off > 0; off >>= 1) s += __shfl_down(s, off);
        const int lane = t & 63, w = t >> 6;
        if (lane == 0) tile[0][w] = s;
        __syncthreads();
        if (t == 0) x_sq[b] = tile[0][0] + tile[0][1] + tile[0][2] + tile[0][3];
        return;
    }

    const int r  = blockIdx.z;
    const int c0 = blockIdx.x * 64;
    const int d0 = blockIdx.y * 64;
    const int g  = t >> 4;
    const int cc = (t & 15) * 4;

    const float* Wp = W + (size_t)(r * IN_DIM + d0 + g) * IN_DIM + c0 + cc;
#pragma unroll
    for (int p = 0; p < 4; ++p) {
        const float4 v = *(const float4*)(Wp + (size_t)(16 * p) * IN_DIM);
        const int dl = g + 16 * p;
        tile[dl][cc]     = v.x;
        tile[dl][cc + 1] = v.y;
        tile[dl][cc + 2] = v.z;
        tile[dl][cc + 3] = v.w;
    }
    __syncthreads();

    const int c8 = t & 7;                 // k-chunk within the 64-d tile
    const int gm = gmem_of(c8);
#pragma unroll
    for (int p = 0; p < 2; ++p) {
        const int cr = (t >> 3) + 32 * p; // c-row 0..63
        float v[8];
        float ss = 0.f;
#pragma unroll
        for (int j = 0; j < 8; ++j) {     // banks (8c8+j+cr)%32 -> 2-way, free
            v[j] = tile[8 * c8 + j][cr];
            ss += v[j] * v[j];
        }
        const int o = 2 * (c0 + cr) + r;
        uint2 pk;
        pk.x = pk4(16.f * v[0], 16.f * v[1], 16.f * v[2], 16.f * v[3]);
        pk.y = pk4(16.f * v[4], 16.f * v[5], 16.f * v[6], 16.f * v[7]);
        *(uint2*)(protos + (size_t)o * IN_DIM + d0 + gm * 8) = pk;
        ss += __shfl_xor(ss, 1);
        ss += __shfl_xor(ss, 2);
        ss += __shfl_xor(ss, 4);
        if (c8 == 0) psq_part[(size_t)blockIdx.y * OUT_DIM + o] = ss;
    }
}

// --------------------------------------------------------------------------
// Kernel 2: fp8 GEMM + epilogue — measured-best structure (R7; twice
// verified 106.4/108.7). FINAL after R10-R15 ablation: counted-vmcnt
// pipeline (-8), direct-B (-6), no-LDS (-33), BK=128 (-6), pb-hoist (0),
// T3-min dbuf (-3) — all regressed or neutral. The 2-barrier single-buffer
// loop at 4 blocks/CU is the local optimum: cross-block TLP does the
// latency hiding (m114); the residual stall is the 2-phase schedule's
// structural cost (m233), unbreakable without 8-phase/256²/8-wave
// prerequisites this problem's M=1024 cannot support.
// out[b][o] = 0.125*acc - x_sq[b] - (sum_dt psq_part[dt][o] + bias[o])
// Block 64M x 64N, 1024 blocks (4/CU, 4 waves/SIMD). Wave w: kh=w&1 owns
// K-half, nh=w>>1 owns 32 N-cols; wave tile 64x32 = 4x2 MFMA 16x16x32 fp8.
// LDS row = 128B (2 k-halves x 64B k-interleaved blocks); position swizzle
// p = l ^ (row&7) on the GLOBAL side of global_load_lds -> staging stays
// lane-contiguous, frag b128 reads are 2-way (free, m136).
// R8 lesson: 64x64 wave tiles (acc[4][4]=64 regs) spill under the (256,4)
// 128-VGPR cap -> 556 MB scratch traffic. 4x2 acc is the pressure sweet spot.
// --------------------------------------------------------------------------
extern "C" __global__ __launch_bounds__(256, 4) void gemm_epi(
        const unsigned char* __restrict__ A,
        const unsigned char* __restrict__ Bt,
        const float* __restrict__ x_sq,
        const float* __restrict__ psq_part,
        const float* __restrict__ bias,
        float* __restrict__ out) {
    __shared__ __align__(16) unsigned char smem[16384];
    unsigned char* lA = smem;           // 8 KB: 64 rows x 128 B
    unsigned char* lB = smem + 8192;    // 8 KB

    const int lid = blockIdx.x;          // XCD swizzle: XCD k owns n-tiles [8k,8k+8)
    const int xcd = lid & 7;
    const int wi  = lid >> 3;
    const int nt  = xcd * 8 + (wi & 7);
    const int mt  = wi >> 3;
    const int m0 = mt * 64;
    const int n0 = nt * 64;

    const int t = threadIdx.x;
    // staging: thread t owns LDS bytes [16t,16t+16) and [4096+16t,+16) of
    // lA/lB. off -> row=off>>7, phys pos p=(off>>4)&7; logical l = p^(row&7);
    // l -> k-half l>>2, 16B-chunk l&3 of the row's 64B k-block.
    const int rS = t >> 3;               // row 0..31 (2nd chunk: +32, same &7)
    const int pS = t & 7;
    const int lS = pS ^ (rS & 7);
    const size_t goff = (size_t)(lS >> 2) * 1024 + (lS & 3) * 16;
    const unsigned char* gA0 = A  + (size_t)(m0 + rS) * IN_DIM + goff;
    const unsigned char* gA1 = gA0 + (size_t)32 * IN_DIM;
    const unsigned char* gB0 = Bt + (size_t)(n0 + rS) * IN_DIM + goff;
    const unsigned char* gB1 = gB0 + (size_t)32 * IN_DIM;
    unsigned char* lAd = lA + t * 16;
    unsigned char* lBd = lB + t * 16;

    const int wave = t >> 6;
    const int lane = t & 63;
    const int kh = wave & 1;             // K-half this wave owns
    const int nh = wave >> 1;            // N-half this wave owns
    const int ln = lane & 15;
    const int qd = lane >> 4;
    const int pr = (kh * 4 + qd) ^ (ln & 7);   // phys 16B pos for frag reads

    f32x4 acc[4][2] = {};

    for (int it = 0; it < 16; ++it) {    // BK=64 per half per iter
        async16(gA0, lAd); async16(gA1, lAd + 4096);
        async16(gB0, lBd); async16(gB1, lBd + 4096);
        gA0 += 64; gA1 += 64; gB0 += 64; gB1 += 64;
        __syncthreads();                 // vmcnt drain: tile visible

        llx2 af[4], bf[2];
#pragma unroll
        for (int i = 0; i < 4; ++i)
            af[i] = *(const llx2*)(lA + (i * 16 + ln) * 128 + pr * 16);
#pragma unroll
        for (int j = 0; j < 2; ++j)
            bf[j] = *(const llx2*)(lB + (nh * 32 + j * 16 + ln) * 128 + pr * 16);
#pragma unroll
        for (int kk = 0; kk < 2; ++kk)
#pragma unroll
            for (int i = 0; i < 4; ++i)
#pragma unroll
                for (int j = 0; j < 2; ++j)
                    acc[i][j] = __builtin_amdgcn_mfma_f32_16x16x32_fp8_fp8(
                                    af[i][kk], bf[j][kk], acc[i][j], 0, 0, 0);
        __syncthreads();                 // reads done before next stage
    }

    // cross-K-half reduction: kh=1 waves dump acc to LDS, kh=0 waves finish.
    if (kh == 1) {
#pragma unroll
        for (int i = 0; i < 4; ++i)
#pragma unroll
            for (int j = 0; j < 2; ++j)
                *(f32x4*)(smem + nh * 8192 + (i * 2 + j) * 1024 + lane * 16) =
                    acc[i][j];
    }
    __syncthreads();
    if (kh == 0) {
#pragma unroll
        for (int j = 0; j < 2; ++j) {
            const int col = n0 + nh * 32 + j * 16 + ln;
            float pb = bias[col];
#pragma unroll
            for (int dt = 0; dt < 32; ++dt)
                pb += psq_part[(size_t)dt * OUT_DIM + col];
#pragma unroll
            for (int i = 0; i < 4; ++i) {
                const f32x4 o4 = *(const f32x4*)(smem + nh * 8192 +
                                                 (i * 2 + j) * 1024 + lane * 16);
                const int row0 = m0 + i * 16 + qd * 4;
#pragma unroll
                for (int rr = 0; rr < 4; ++rr) {
                    const int row = row0 + rr;
                    out[(size_t)row * OUT_DIM + col] =
                        0.125f * (acc[i][j][rr] + o4[rr]) - x_sq[row] - pb;
                }
            }
        }
    }
}

// --------------------------------------------------------------------------
extern "C" void kernel_launch(void* const* d_in, const int* in_sizes, int n_in,
                              void* d_out, int out_size, void* d_ws, size_t ws_size,
                              hipStream_t stream) {
    const float* x    = (const float*)d_in[0];   // [1024, 2048]
    const float* W    = (const float*)d_in[1];   // [4096, 2048]
    const float* bias = (const float*)d_in[2];   // [4096]
    float* out = (float*)d_out;

    char* ws = (char*)d_ws;
    unsigned char* protos = (unsigned char*)ws;                               // 8 MB
    unsigned char* xb     = (unsigned char*)(ws + (size_t)8 * 1024 * 1024);   // 2 MB
    float* x_sq           = (float*)(ws + (size_t)10 * 1024 * 1024);          // 4 KB
    float* psq_part       = (float*)(ws + (size_t)10 * 1024 * 1024 + 65536);  // 512 KB

    prep<<<dim3(32, 32, 3), 256, 0, stream>>>(W, x, protos, xb, psq_part, x_sq);
    gemm_epi<<<dim3(1024), 256, 0, stream>>>(xb, protos, x_sq, psq_part, bias, out);
}